// Round 5
// baseline (161.467 us; speedup 1.0000x reference)
//
#include <hip/hip_runtime.h>
#include <math.h>

#define B_DIM 8
#define S_DIM 4096
#define D_DIM 1024
#define N_DIM 16
#define ROWS (B_DIM * S_DIM)          // 32768

#define CHUNK_L 32
#define WARM 64
#define STEPS (CHUNK_L + WARM)        // 96 sequential steps per chain
#define NCHAIN (B_DIM * (S_DIM / CHUNK_L))   // 1024 chains

// ---------------------------------------------------------------------------
// Kernel 1: CW[n][d] = sum_k C[n][k] * W[d][k]   (round-1 proven, unchanged)
// ---------------------------------------------------------------------------
__global__ __launch_bounds__(256) void k_cw(const float* __restrict__ C,
                                            const float* __restrict__ W,
                                            float* __restrict__ CW) {
    int u = blockIdx.x * 256 + threadIdx.x;
    int d = u >> 4;
    int n = u & 15;
    const float* crow = C + n * D_DIM;
    const float* wrow = W + (size_t)d * D_DIM;
    float acc = 0.f;
#pragma unroll 4
    for (int k = 0; k < D_DIM; k += 4) {
        float4 c4 = *(const float4*)(crow + k);
        float4 w4 = *(const float4*)(wrow + k);
        acc = fmaf(c4.x, w4.x, acc);
        acc = fmaf(c4.y, w4.y, acc);
        acc = fmaf(c4.z, w4.z, acc);
        acc = fmaf(c4.w, w4.w, acc);
    }
    CW[n * D_DIM + d] = acc;
}

// ---------------------------------------------------------------------------
// Kernel 2 (REWRITTEN): xb_part[r][n] = sum_{k in half} x[r][k] * B[k][n]
// Register-blocked 4 rows x 4 n per thread; ALL LDS traffic is ds_read_b128.
// x-tile in LDS as [256 rows][64 k] with float4-block swizzle
//   kb' = kb ^ ((row>>2)&7)   (applied on store AND load -> consistent),
// which spreads both staging b128-writes and read-phase b128-reads evenly
// across banks (2 words/bank). Grid = 128 row-tiles x 2 k-halves = 256.
// ---------------------------------------------------------------------------
#define RT 256
#define KT 64
__global__ __launch_bounds__(256) void k_xb2(const float* __restrict__ x,
                                             const float* __restrict__ Bm,
                                             float* __restrict__ xb_a,
                                             float* __restrict__ xb_b) {
    __shared__ float xs[RT * KT];      // 64 KB, swizzled float4 blocks
    __shared__ float bs[KT][20];       // 5 KB, padded rows (16B-aligned)
    const int t = threadIdx.x;
    const int rt = blockIdx.x >> 1;
    const int kh = blockIdx.x & 1;
    const int row0 = rt * RT;
    const int rg = t >> 2;             // 0..63 -> rows rg*4 .. rg*4+3
    const int nq = (t & 3) * 4;
    float* outp = kh ? xb_b : xb_a;

    float4 acc[4];
#pragma unroll
    for (int i = 0; i < 4; ++i) acc[i] = {0.f, 0.f, 0.f, 0.f};

    for (int kc = 0; kc < 8; ++kc) {
        const int kbase = kh * 512 + kc * 64;
        __syncthreads();               // protect xs/bs reuse from prev iter
        // stage x: 4096 float4, 16 per thread; batch loads then stores
        float4 v[16];
#pragma unroll
        for (int p = 0; p < 16; ++p) {
            int fid = p * 256 + t;
            int r = fid >> 4;          // 0..255
            int q = fid & 15;          // k-block within tile
            v[p] = *(const float4*)(x + (size_t)(row0 + r) * D_DIM + kbase + q * 4);
        }
#pragma unroll
        for (int p = 0; p < 16; ++p) {
            int fid = p * 256 + t;
            int r = fid >> 4;
            int q = fid & 15;
            int kb = q ^ ((r >> 2) & 7);
            *(float4*)(xs + r * KT + kb * 4) = v[p];
        }
        // stage B tile (64 x 16)
        {
            int r = t >> 2;            // 0..63
            int q = (t & 3) * 4;
            float4 bv = *(const float4*)(Bm + (size_t)(kbase + r) * N_DIM + q);
            *(float4*)(&bs[r][q]) = bv;
        }
        __syncthreads();
        // read phase: per k-quad, 4 b128 of B + 4 b128 of x, 64 FMAs
#pragma unroll 4
        for (int k4 = 0; k4 < 16; ++k4) {
            float4 bv[4];
#pragma unroll
            for (int j = 0; j < 4; ++j)
                bv[j] = *(const float4*)(&bs[k4 * 4 + j][nq]);
            const int kb = k4 ^ (rg & 7);
#pragma unroll
            for (int i = 0; i < 4; ++i) {
                int r = rg * 4 + i;
                float4 xv = *(const float4*)(xs + r * KT + kb * 4);
                acc[i].x = fmaf(xv.x, bv[0].x, acc[i].x);
                acc[i].y = fmaf(xv.x, bv[0].y, acc[i].y);
                acc[i].z = fmaf(xv.x, bv[0].z, acc[i].z);
                acc[i].w = fmaf(xv.x, bv[0].w, acc[i].w);
                acc[i].x = fmaf(xv.y, bv[1].x, acc[i].x);
                acc[i].y = fmaf(xv.y, bv[1].y, acc[i].y);
                acc[i].z = fmaf(xv.y, bv[1].z, acc[i].z);
                acc[i].w = fmaf(xv.y, bv[1].w, acc[i].w);
                acc[i].x = fmaf(xv.z, bv[2].x, acc[i].x);
                acc[i].y = fmaf(xv.z, bv[2].y, acc[i].y);
                acc[i].z = fmaf(xv.z, bv[2].z, acc[i].z);
                acc[i].w = fmaf(xv.z, bv[2].w, acc[i].w);
                acc[i].x = fmaf(xv.w, bv[3].x, acc[i].x);
                acc[i].y = fmaf(xv.w, bv[3].y, acc[i].y);
                acc[i].z = fmaf(xv.w, bv[3].z, acc[i].z);
                acc[i].w = fmaf(xv.w, bv[3].w, acc[i].w);
            }
        }
    }
#pragma unroll
    for (int i = 0; i < 4; ++i)
        *(float4*)(outp + (size_t)(row0 + rg * 4 + i) * N_DIM + nq) = acc[i];
}

// ---------------------------------------------------------------------------
// Kernel 2b: xb = xb_a + xb_b  (2-term adds, deterministic; ~1.5 us)
// ---------------------------------------------------------------------------
__global__ __launch_bounds__(256) void k_add(const float* __restrict__ xb_a,
                                             const float* __restrict__ xb_b,
                                             float* __restrict__ xb) {
    int i = (blockIdx.x * 256 + threadIdx.x) * 4;
    float4 a = *(const float4*)(xb_a + i);
    float4 b = *(const float4*)(xb_b + i);
    float4 s = {a.x + b.x, a.y + b.y, a.z + b.z, a.w + b.w};
    *(float4*)(xb + i) = s;
}

// ---------------------------------------------------------------------------
// Kernel 3: chunked scan (round-4 proven, UNCHANGED for attribution)
// ---------------------------------------------------------------------------
__global__ __launch_bounds__(256) void k_scan(const float* __restrict__ xb,
                                              const float* __restrict__ A,
                                              float* __restrict__ hs) {
    const int tid = threadIdx.x;
    const int lane = tid & 63;
    const int n = tid & 15;
    const int base4 = (lane & 48) * 4;

    const int chain = blockIdx.x * 16 + (tid >> 4);
    const int b = chain >> 7;
    const int chunk = chain & 127;
    const int t0 = chunk * CHUNK_L - WARM;

    float Ar[16];
#pragma unroll
    for (int m4 = 0; m4 < 16; m4 += 4) {
        float4 v = *(const float4*)(A + n * 16 + m4);
        Ar[m4 + 0] = v.x; Ar[m4 + 1] = v.y; Ar[m4 + 2] = v.z; Ar[m4 + 3] = v.w;
    }

    const float* xp = xb + (size_t)b * S_DIM * N_DIM + n;
    float* hp = hs + (size_t)b * S_DIM * N_DIM + n;

    float ring[8];
#pragma unroll
    for (int i = 0; i < 8; ++i) {
        int tt = t0 + i;
        ring[i] = (tt >= 0) ? xp[(size_t)tt * N_DIM] : 0.f;
    }

    float h = 0.f;
    for (int tr0 = 0; tr0 < STEPS; tr0 += 8) {
#pragma unroll
        for (int j = 0; j < 8; ++j) {
            const int tr = tr0 + j;
            const float xv = ring[j];
            const int hbits = __float_as_int(h);
            int hm[16];
#pragma unroll
            for (int m = 0; m < 16; ++m)
                hm[m] = __builtin_amdgcn_ds_bpermute(base4 + m * 4, hbits);
            float acc0 = xv, acc1 = 0.f;
#pragma unroll
            for (int m = 0; m < 8; ++m) {
                acc0 = fmaf(Ar[m], __int_as_float(hm[m]), acc0);
                acc1 = fmaf(Ar[m + 8], __int_as_float(hm[m + 8]), acc1);
            }
            float g = acc0 + acc1;
            float ax = fabsf(g);
            float e = __expf(2.f * ax);
            float tv = 1.f - 2.f / (e + 1.f);
            h = (g < 0.f) ? -tv : tv;
            if (tr >= WARM)
                hp[(size_t)(t0 + tr) * N_DIM] = h;
            int tt = t0 + tr + 8;
            if (tr + 8 < STEPS)
                ring[j] = (tt >= 0) ? xp[(size_t)tt * N_DIM] : 0.f;
        }
    }
}

// ---------------------------------------------------------------------------
// Kernel 4: out[r][d] = sum_n hs[r][n] * CW[n][d] + bias[d]  (unchanged)
// ---------------------------------------------------------------------------
__global__ __launch_bounds__(256) void k_out(const float* __restrict__ hs,
                                             const float* __restrict__ CW,
                                             const float* __restrict__ bias,
                                             float* __restrict__ out) {
    const int t = threadIdx.x;
    const int d0 = t * 4;
    const int row0 = blockIdx.x * 32;
    float4 cw[16];
#pragma unroll
    for (int nn = 0; nn < 16; ++nn)
        cw[nn] = *(const float4*)(CW + nn * D_DIM + d0);
    float4 b4 = *(const float4*)(bias + d0);

    for (int r = row0; r < row0 + 32; ++r) {
        const float4* hp = (const float4*)(hs + (size_t)r * N_DIM);
        float4 h0 = hp[0], h1 = hp[1], h2 = hp[2], h3 = hp[3];
        float hv[16] = {h0.x, h0.y, h0.z, h0.w, h1.x, h1.y, h1.z, h1.w,
                        h2.x, h2.y, h2.z, h2.w, h3.x, h3.y, h3.z, h3.w};
        float4 acc = b4;
#pragma unroll
        for (int nn = 0; nn < 16; ++nn) {
            acc.x = fmaf(hv[nn], cw[nn].x, acc.x);
            acc.y = fmaf(hv[nn], cw[nn].y, acc.y);
            acc.z = fmaf(hv[nn], cw[nn].z, acc.z);
            acc.w = fmaf(hv[nn], cw[nn].w, acc.w);
        }
        *(float4*)(out + (size_t)r * D_DIM + d0) = acc;
    }
}

// ---------------------------------------------------------------------------
extern "C" void kernel_launch(void* const* d_in, const int* in_sizes, int n_in,
                              void* d_out, int out_size, void* d_ws,
                              size_t ws_size, hipStream_t stream) {
    const float* x    = (const float*)d_in[0];   // [8,4096,1024]
    const float* A    = (const float*)d_in[1];   // [16,16]
    const float* Bm   = (const float*)d_in[2];   // [1024,16]
    const float* C    = (const float*)d_in[3];   // [16,1024]
    const float* W    = (const float*)d_in[4];   // [1024,1024]
    const float* bias = (const float*)d_in[5];   // [1024]
    float* out = (float*)d_out;

    float* ws   = (float*)d_ws;
    float* xb   = ws;                   // 524288 floats (summed)
    float* hs   = ws + 524288;          // 524288
    float* CW   = ws + 1048576;         // 16384
    float* xb_a = ws + 1064960;         // 524288
    float* xb_b = ws + 1589248;         // 524288

    k_cw<<<dim3((N_DIM * D_DIM) / 256), dim3(256), 0, stream>>>(C, W, CW);
    k_xb2<<<dim3((ROWS / RT) * 2), dim3(256), 0, stream>>>(x, Bm, xb_a, xb_b);
    k_add<<<dim3(ROWS * N_DIM / 1024), dim3(256), 0, stream>>>(xb_a, xb_b, xb);
    k_scan<<<dim3(NCHAIN / 16), dim3(256), 0, stream>>>(xb, A, hs);
    k_out<<<dim3(ROWS / 32), dim3(256), 0, stream>>>(hs, CW, bias, out);
}

// Round 6
// 121.560 us; speedup vs baseline: 1.3283x; 1.3283x over previous
//
#include <hip/hip_runtime.h>
#include <math.h>

#define B_DIM 8
#define S_DIM 4096
#define D_DIM 1024
#define N_DIM 16
#define ROWS (B_DIM * S_DIM)          // 32768

#define CHUNK_L 32
#define WARM 64
#define STEPS (CHUNK_L + WARM)        // 96 sequential steps per chain
#define NCHAIN (B_DIM * (S_DIM / CHUNK_L))   // 1024 chains

#define TILE_R 64
#define TILE_K 64
#define XB_BLOCKS (ROWS / TILE_R)     // 512
#define CW_BLOCKS ((N_DIM * D_DIM) / 256)  // 64

// ---------------------------------------------------------------------------
// Kernel 1 (fused): blocks [0, XB_BLOCKS) do the xb GEMM (round-1 proven);
// blocks [XB_BLOCKS, XB_BLOCKS+CW_BLOCKS) compute CW[n][d] = sum_k C[n][k]*W[d][k].
// Independent work, one launch — cw (~3 us) hides under xb (~25 us).
// ---------------------------------------------------------------------------
__global__ __launch_bounds__(256) void k_xbcw(const float* __restrict__ x,
                                              const float* __restrict__ Bm,
                                              float* __restrict__ xb,
                                              const float* __restrict__ C,
                                              const float* __restrict__ W,
                                              float* __restrict__ CW) {
    const int t = threadIdx.x;
    if (blockIdx.x >= XB_BLOCKS) {
        // ---- CW part (round-1 proven k_cw) ----
        int u = (blockIdx.x - XB_BLOCKS) * 256 + t;
        int d = u >> 4;
        int n = u & 15;
        const float* crow = C + n * D_DIM;
        const float* wrow = W + (size_t)d * D_DIM;
        float acc = 0.f;
#pragma unroll 4
        for (int k = 0; k < D_DIM; k += 4) {
            float4 c4 = *(const float4*)(crow + k);
            float4 w4 = *(const float4*)(wrow + k);
            acc = fmaf(c4.x, w4.x, acc);
            acc = fmaf(c4.y, w4.y, acc);
            acc = fmaf(c4.z, w4.z, acc);
            acc = fmaf(c4.w, w4.w, acc);
        }
        CW[n * D_DIM + d] = acc;
        return;
    }
    // ---- xb part (round-1 proven k_xb) ----
    __shared__ float xs[TILE_R][68];
    __shared__ float bs[TILE_K][20];
    const int row0 = blockIdx.x * TILE_R;
    const int row = t >> 2;
    const int nq = (t & 3) * 4;
    float4 acc = {0.f, 0.f, 0.f, 0.f};

    for (int kc = 0; kc < D_DIM; kc += TILE_K) {
#pragma unroll
        for (int p = 0; p < 4; ++p) {
            int fid = p * 256 + t;
            int r = fid >> 4;
            int q = (fid & 15) * 4;
            float4 v = *(const float4*)(x + (size_t)(row0 + r) * D_DIM + kc + q);
            xs[r][q + 0] = v.x; xs[r][q + 1] = v.y;
            xs[r][q + 2] = v.z; xs[r][q + 3] = v.w;
        }
        {
            int r = t >> 2;
            int q = (t & 3) * 4;
            float4 v = *(const float4*)(Bm + (size_t)(kc + r) * N_DIM + q);
            bs[r][q + 0] = v.x; bs[r][q + 1] = v.y;
            bs[r][q + 2] = v.z; bs[r][q + 3] = v.w;
        }
        __syncthreads();
#pragma unroll 8
        for (int kk = 0; kk < TILE_K; ++kk) {
            float xv = xs[row][kk];
            acc.x = fmaf(xv, bs[kk][nq + 0], acc.x);
            acc.y = fmaf(xv, bs[kk][nq + 1], acc.y);
            acc.z = fmaf(xv, bs[kk][nq + 2], acc.z);
            acc.w = fmaf(xv, bs[kk][nq + 3], acc.w);
        }
        __syncthreads();
    }
    *(float4*)(xb + (size_t)(row0 + row) * N_DIM + nq) = acc;
}

// ---------------------------------------------------------------------------
// Kernel 2: chunked scan — SAME math/chains as round 4 (attribution), but
// 64-thread blocks x 256 blocks: 1 wave per CU on all 256 CUs instead of
// 4 waves on 64 CUs -> DS-pipe (bpermute) work per CU drops 4x.
// ---------------------------------------------------------------------------
__global__ __launch_bounds__(64) void k_scan(const float* __restrict__ xb,
                                             const float* __restrict__ A,
                                             float* __restrict__ hs) {
    const int tid = threadIdx.x;           // 0..63
    const int n = tid & 15;
    const int base4 = (tid & 48) * 4;      // byte addr of group base lane

    const int chain = blockIdx.x * 4 + (tid >> 4);   // 0..1023
    const int b = chain >> 7;
    const int chunk = chain & 127;
    const int t0 = chunk * CHUNK_L - WARM;

    float Ar[16];
#pragma unroll
    for (int m4 = 0; m4 < 16; m4 += 4) {
        float4 v = *(const float4*)(A + n * 16 + m4);
        Ar[m4 + 0] = v.x; Ar[m4 + 1] = v.y; Ar[m4 + 2] = v.z; Ar[m4 + 3] = v.w;
    }

    const float* xp = xb + (size_t)b * S_DIM * N_DIM + n;
    float* hp = hs + (size_t)b * S_DIM * N_DIM + n;

    float ring[8];
#pragma unroll
    for (int i = 0; i < 8; ++i) {
        int tt = t0 + i;
        ring[i] = (tt >= 0) ? xp[(size_t)tt * N_DIM] : 0.f;
    }

    float h = 0.f;
    for (int tr0 = 0; tr0 < STEPS; tr0 += 8) {
#pragma unroll
        for (int j = 0; j < 8; ++j) {
            const int tr = tr0 + j;
            const float xv = ring[j];
            const int hbits = __float_as_int(h);
            int hm[16];
#pragma unroll
            for (int m = 0; m < 16; ++m)
                hm[m] = __builtin_amdgcn_ds_bpermute(base4 + m * 4, hbits);
            float acc0 = xv, acc1 = 0.f;
#pragma unroll
            for (int m = 0; m < 8; ++m) {
                acc0 = fmaf(Ar[m], __int_as_float(hm[m]), acc0);
                acc1 = fmaf(Ar[m + 8], __int_as_float(hm[m + 8]), acc1);
            }
            float g = acc0 + acc1;
            float ax = fabsf(g);
            float e = __expf(2.f * ax);
            float tv = 1.f - 2.f / (e + 1.f);
            h = (g < 0.f) ? -tv : tv;
            if (tr >= WARM)
                hp[(size_t)(t0 + tr) * N_DIM] = h;
            int tt = t0 + tr + 8;
            if (tr + 8 < STEPS)
                ring[j] = (tt >= 0) ? xp[(size_t)tt * N_DIM] : 0.f;
        }
    }
}

// ---------------------------------------------------------------------------
// Kernel 3: out[r][d] = sum_n hs[r][n] * CW[n][d] + bias[d]  (round-1 proven)
// ---------------------------------------------------------------------------
__global__ __launch_bounds__(256) void k_out(const float* __restrict__ hs,
                                             const float* __restrict__ CW,
                                             const float* __restrict__ bias,
                                             float* __restrict__ out) {
    const int t = threadIdx.x;
    const int d0 = t * 4;
    const int row0 = blockIdx.x * 32;
    float4 cw[16];
#pragma unroll
    for (int nn = 0; nn < 16; ++nn)
        cw[nn] = *(const float4*)(CW + nn * D_DIM + d0);
    float4 b4 = *(const float4*)(bias + d0);

    for (int r = row0; r < row0 + 32; ++r) {
        const float4* hp = (const float4*)(hs + (size_t)r * N_DIM);
        float4 h0 = hp[0], h1 = hp[1], h2 = hp[2], h3 = hp[3];
        float hv[16] = {h0.x, h0.y, h0.z, h0.w, h1.x, h1.y, h1.z, h1.w,
                        h2.x, h2.y, h2.z, h2.w, h3.x, h3.y, h3.z, h3.w};
        float4 acc = b4;
#pragma unroll
        for (int nn = 0; nn < 16; ++nn) {
            acc.x = fmaf(hv[nn], cw[nn].x, acc.x);
            acc.y = fmaf(hv[nn], cw[nn].y, acc.y);
            acc.z = fmaf(hv[nn], cw[nn].z, acc.z);
            acc.w = fmaf(hv[nn], cw[nn].w, acc.w);
        }
        *(float4*)(out + (size_t)r * D_DIM + d0) = acc;
    }
}

// ---------------------------------------------------------------------------
extern "C" void kernel_launch(void* const* d_in, const int* in_sizes, int n_in,
                              void* d_out, int out_size, void* d_ws,
                              size_t ws_size, hipStream_t stream) {
    const float* x    = (const float*)d_in[0];   // [8,4096,1024]
    const float* A    = (const float*)d_in[1];   // [16,16]
    const float* Bm   = (const float*)d_in[2];   // [1024,16]
    const float* C    = (const float*)d_in[3];   // [16,1024]
    const float* W    = (const float*)d_in[4];   // [1024,1024]
    const float* bias = (const float*)d_in[5];   // [1024]
    float* out = (float*)d_out;

    float* ws = (float*)d_ws;
    float* xb = ws;                            // 524288 floats
    float* hs = ws + 524288;                   // 524288 floats
    float* CW = ws + 1048576;                  // 16384 floats

    k_xbcw<<<dim3(XB_BLOCKS + CW_BLOCKS), dim3(256), 0, stream>>>(x, Bm, xb, C, W, CW);
    k_scan<<<dim3(NCHAIN / 4), dim3(64), 0, stream>>>(xb, A, hs);
    k_out<<<dim3(ROWS / 32), dim3(256), 0, stream>>>(hs, CW, bias, out);
}